// Round 1
// 1284.627 us; speedup vs baseline: 1.0340x; 1.0340x over previous
//
#include <hip/hip_runtime.h>

#define CC 128     // channels
#define C4V 32     // float4 per row
#define RPB 1024   // rows per pool block
#define UNR 8      // rows unrolled per thread per outer iteration

typedef float f4v __attribute__((ext_vector_type(4)));

__device__ __forceinline__ f4v vsplat(float x) {
    f4v r; r.x = x; r.y = x; r.z = x; r.w = x; return r;
}

__device__ __forceinline__ unsigned fkey(float f) {
    unsigned b = __float_as_uint(f);
    return (b & 0x80000000u) ? ~b : (b | 0x80000000u);
}
__device__ __forceinline__ float fdec(unsigned k) {
    unsigned b = (k & 0x80000000u) ? (k & 0x7FFFFFFFu) : ~k;
    return __uint_as_float(b);
}

__device__ __forceinline__ void flush_seg(int seg, int c4, const f4v& sum, const f4v& mx,
                                          int cnt, float* __restrict__ seg_sum,
                                          unsigned* __restrict__ seg_maxk, int* __restrict__ seg_cnt) {
    float* sp = seg_sum + (size_t)seg * CC + c4 * 4;
    atomicAdd(sp + 0, sum.x);
    atomicAdd(sp + 1, sum.y);
    atomicAdd(sp + 2, sum.z);
    atomicAdd(sp + 3, sum.w);
    unsigned* mp = seg_maxk + (size_t)seg * CC + c4 * 4;
    atomicMax(mp + 0, fkey(mx.x));
    atomicMax(mp + 1, fkey(mx.y));
    atomicMax(mp + 2, fkey(mx.z));
    atomicMax(mp + 3, fkey(mx.w));
    if (c4 == 0) atomicAdd(&seg_cnt[seg], cnt);
}

__global__ void __launch_bounds__(256) pool_kernel(
    const float* __restrict__ feats, const int* __restrict__ ids, int N,
    float* __restrict__ seg_sum, unsigned* __restrict__ seg_maxk,
    int* __restrict__ seg_cnt)
{
    __shared__ int sids[RPB];

    const int c4 = threadIdx.x & 31;   // which float4 of the row
    const int rl = threadIdx.x >> 5;   // row-lane 0..7
    const long long r0 = (long long)blockIdx.x * RPB;
    const int nrows = (r0 + RPB <= N) ? RPB : (int)(N - r0);

    // Stage this block's ids into LDS (coalesced, once). Inner loop then has
    // a single VMEM stream (the feature loads).
    for (int i = threadIdx.x; i < nrows; i += 256)
        sids[i] = ids[r0 + i];
    __syncthreads();

    f4v sum = vsplat(0.f);
    f4v mx  = vsplat(-3.4e38f);
    int cur = -1, cnt = 0;

    // Pointer at (row r0+rl, float4 c4)
    const f4v* __restrict__ fp = (const f4v*)feats + ((long long)r0 + rl) * C4V + c4;

    if (nrows == RPB) {
        #pragma unroll 1
        for (int it = 0; it < RPB / (8 * UNR); ++it) {
            const int lb = it * (8 * UNR) + rl;   // local row of k=0

            // Issue all 8 independent 16B loads first -> 8 KB in flight / wave.
            f4v v[UNR];
            #pragma unroll
            for (int k = 0; k < UNR; ++k)
                v[k] = __builtin_nontemporal_load(fp + (size_t)(it * (8 * UNR) + 8 * k) * C4V);

            int idv[UNR];
            #pragma unroll
            for (int k = 0; k < UNR; ++k)
                idv[k] = sids[lb + 8 * k];

            bool same = true;
            #pragma unroll
            for (int k = 0; k < UNR; ++k) same &= (idv[k] == cur);

            if (same) {
                // Fast path: avg segment length ~7812 rows -> taken ~99% of the time.
                #pragma unroll
                for (int k = 0; k < UNR; ++k) {
                    sum.x += v[k].x; sum.y += v[k].y; sum.z += v[k].z; sum.w += v[k].w;
                    mx.x = fmaxf(mx.x, v[k].x); mx.y = fmaxf(mx.y, v[k].y);
                    mx.z = fmaxf(mx.z, v[k].z); mx.w = fmaxf(mx.w, v[k].w);
                }
                cnt += UNR;
            } else {
                #pragma unroll
                for (int k = 0; k < UNR; ++k) {
                    if (idv[k] != cur) {
                        if (cur >= 0)
                            flush_seg(cur, c4, sum, mx, cnt, seg_sum, seg_maxk, seg_cnt);
                        cur = idv[k];
                        sum = vsplat(0.f);
                        mx  = vsplat(-3.4e38f);
                        cnt = 0;
                    }
                    sum.x += v[k].x; sum.y += v[k].y; sum.z += v[k].z; sum.w += v[k].w;
                    mx.x = fmaxf(mx.x, v[k].x); mx.y = fmaxf(mx.y, v[k].y);
                    mx.z = fmaxf(mx.z, v[k].z); mx.w = fmaxf(mx.w, v[k].w);
                    cnt++;
                }
            }
        }
    } else {
        // Tail block: simple bounds-checked per-row loop.
        for (int lr = rl; lr < nrows; lr += 8) {
            int id = sids[lr];
            f4v v = fp[(size_t)(lr - rl) * C4V];
            if (id != cur) {
                if (cur >= 0)
                    flush_seg(cur, c4, sum, mx, cnt, seg_sum, seg_maxk, seg_cnt);
                cur = id;
                sum = vsplat(0.f);
                mx  = vsplat(-3.4e38f);
                cnt = 0;
            }
            sum.x += v.x; sum.y += v.y; sum.z += v.z; sum.w += v.w;
            mx.x = fmaxf(mx.x, v.x); mx.y = fmaxf(mx.y, v.y);
            mx.z = fmaxf(mx.z, v.z); mx.w = fmaxf(mx.w, v.w);
            cnt++;
        }
    }
    if (cur >= 0)
        flush_seg(cur, c4, sum, mx, cnt, seg_sum, seg_maxk, seg_cnt);
}

__global__ void __launch_bounds__(128) head_kernel(
    const float* __restrict__ seg_sum, const unsigned* __restrict__ seg_maxk,
    const int* __restrict__ seg_cnt,
    const float* __restrict__ W1, const float* __restrict__ b1,
    const float* __restrict__ W2, const float* __restrict__ b2,
    const float* __restrict__ W3, const float* __restrict__ b3,
    const float* __restrict__ W4, const float* __restrict__ b4,
    float* __restrict__ out)
{
    __shared__ float pooled[2 * CC];
    __shared__ float h1s[128];
    __shared__ float h2s[64];
    __shared__ float h3s[32];

    const int b = blockIdx.x;
    const int t = threadIdx.x;   // 0..127

    const int cnt = seg_cnt[b];
    const float inv = (cnt > 0) ? (1.f / (float)cnt) : 0.f;

    {
        float s = seg_sum[(size_t)b * CC + t];
        unsigned k = seg_maxk[(size_t)b * CC + t];
        pooled[t] = s * inv;                              // 0 for empty segments
        pooled[CC + t] = (cnt > 0) ? fdec(k) : 0.f;
    }
    __syncthreads();

    {   // 256 -> 128
        float acc = b1[t];
        for (int i = 0; i < 2 * CC; i++) acc += pooled[i] * W1[i * 128 + t];
        h1s[t] = fmaxf(acc, 0.f);
    }
    __syncthreads();

    if (t < 64) {   // 128 -> 64
        float acc = b2[t];
        for (int i = 0; i < 128; i++) acc += h1s[i] * W2[i * 64 + t];
        h2s[t] = fmaxf(acc, 0.f);
    }
    __syncthreads();

    if (t < 32) {   // 64 -> 32
        float acc = b3[t];
        for (int i = 0; i < 64; i++) acc += h2s[i] * W3[i * 32 + t];
        h3s[t] = fmaxf(acc, 0.f);
    }
    __syncthreads();

    if (t < 4) {    // 32 -> 4
        float acc = b4[t];
        for (int i = 0; i < 32; i++) acc += h3s[i] * W4[i * 4 + t];
        out[b * 4 + t] = acc;
    }
}

extern "C" void kernel_launch(void* const* d_in, const int* in_sizes, int n_in,
                              void* d_out, int out_size, void* d_ws, size_t ws_size,
                              hipStream_t stream) {
    const float* feats = (const float*)d_in[0];
    const int*   ids   = (const int*)d_in[1];
    // d_in[2] = batch_size scalar (on device; value derived from out_size instead)
    const float* W1 = (const float*)d_in[3];
    const float* b1 = (const float*)d_in[4];
    const float* W2 = (const float*)d_in[5];
    const float* b2 = (const float*)d_in[6];
    const float* W3 = (const float*)d_in[7];
    const float* b3 = (const float*)d_in[8];
    const float* W4 = (const float*)d_in[9];
    const float* b4 = (const float*)d_in[10];
    float* out = (float*)d_out;

    const int N = in_sizes[1];
    const int NCLS = in_sizes[10];         // 4
    const int B = out_size / NCLS;         // 256

    float*    seg_sum  = (float*)d_ws;
    unsigned* seg_maxk = (unsigned*)(seg_sum + (size_t)B * CC);
    int*      seg_cnt  = (int*)(seg_maxk + (size_t)B * CC);
    const size_t init_bytes = (size_t)B * CC * 4 * 2 + (size_t)B * 4;
    hipMemsetAsync(d_ws, 0, init_bytes, stream);

    const int grid = (N + RPB - 1) / RPB;
    pool_kernel<<<grid, 256, 0, stream>>>(feats, ids, N, seg_sum, seg_maxk, seg_cnt);
    head_kernel<<<B, 128, 0, stream>>>(seg_sum, seg_maxk, seg_cnt,
                                       W1, b1, W2, b2, W3, b3, W4, b4, out);
}